// Round 1
// baseline (1699.671 us; speedup 1.0000x reference)
//
#include <hip/hip_runtime.h>

#define BSZ  4
#define LSEQ 1024
#define CIN  512
#define C2   1024
#define NH   8
#define DQK  32
#define DV   64
#define RELW 2047   // 2*L-1
#define GEPS 1e-4f

#define BI 32
#define BJ 64
#define RW 95       // BI+BJ-1

// ---------------- K1: qkv = x @ W   (M=4096, K=512, N=1024), f32 tiled ----------------
__global__ __launch_bounds__(256) void gemm_qkv(const float* __restrict__ x,
                                                const float* __restrict__ W,
                                                float* __restrict__ qkv) {
    __shared__ float As[16][64];
    __shared__ float Bs[16][64];
    const int t  = threadIdx.x;
    const int tx = t & 15, ty = t >> 4;
    const int m0 = blockIdx.y * 64, n0 = blockIdx.x * 64;
    float acc[4][4] = {};
    for (int k0 = 0; k0 < 512; k0 += 16) {
        {   // A tile: 64 rows x 16 k, 4 threads per row, float4 each
            const int m = t >> 2, kk = (t & 3) * 4;
            const float4 a = *reinterpret_cast<const float4*>(&x[(size_t)(m0 + m) * 512 + k0 + kk]);
            As[kk + 0][m] = a.x; As[kk + 1][m] = a.y; As[kk + 2][m] = a.z; As[kk + 3][m] = a.w;
            // B tile: 16 rows x 64 n, 16 threads per row, float4 each
            const int kb = t >> 4, n = (t & 15) * 4;
            *reinterpret_cast<float4*>(&Bs[kb][n]) =
                *reinterpret_cast<const float4*>(&W[(size_t)(k0 + kb) * 1024 + n0 + n]);
        }
        __syncthreads();
        #pragma unroll
        for (int k = 0; k < 16; ++k) {
            const float4 a = *reinterpret_cast<const float4*>(&As[k][ty * 4]);
            const float4 b = *reinterpret_cast<const float4*>(&Bs[k][tx * 4]);
            const float av[4] = {a.x, a.y, a.z, a.w};
            const float bv[4] = {b.x, b.y, b.z, b.w};
            #pragma unroll
            for (int i = 0; i < 4; ++i)
                #pragma unroll
                for (int j = 0; j < 4; ++j) acc[i][j] += av[i] * bv[j];
        }
        __syncthreads();
    }
    #pragma unroll
    for (int i = 0; i < 4; ++i) {
        const float4 o = {acc[i][0], acc[i][1], acc[i][2], acc[i][3]};
        *reinterpret_cast<float4*>(&qkv[(size_t)(m0 + ty * 4 + i) * 1024 + n0 + tx * 4]) = o;
    }
}

// ---------------- K2/K5: group-norm stats, one block per (b, g) ----------------
template <int CTOT, int GS>
__global__ __launch_bounds__(256) void gn_stats(const float* __restrict__ xin,
                                                float* __restrict__ mean,
                                                float* __restrict__ rstd) {
    const int g = blockIdx.x, b = blockIdx.y;
    const int t = threadIdx.x;
    const int n = LSEQ * GS;
    float s = 0.f, s2 = 0.f;
    for (int idx = t; idx < n; idx += 256) {
        const int l = idx / GS, c = idx % GS;
        const float v = xin[(size_t)(b * LSEQ + l) * CTOT + g * GS + c];
        s += v; s2 += v * v;
    }
    __shared__ float rs[4], rs2[4];
    #pragma unroll
    for (int o = 32; o; o >>= 1) { s += __shfl_down(s, o, 64); s2 += __shfl_down(s2, o, 64); }
    const int w = t >> 6;
    if ((t & 63) == 0) { rs[w] = s; rs2[w] = s2; }
    __syncthreads();
    if (t == 0) {
        s = rs[0] + rs[1] + rs[2] + rs[3];
        s2 = rs2[0] + rs2[1] + rs2[2] + rs2[3];
        const float mu  = s / n;
        const float var = s2 / n - mu * mu;
        mean[b * 32 + g] = mu;
        rstd[b * 32 + g] = rsqrtf(var + GEPS);
    }
}

// ---------------- K3: apply qkv GN + transpose to qkvn[b][c2][l] ----------------
__global__ __launch_bounds__(256) void gn_apply_transpose(const float* __restrict__ qkv,
                                                          const float* __restrict__ mean,
                                                          const float* __restrict__ rstd,
                                                          const float* __restrict__ scale,
                                                          const float* __restrict__ bias,
                                                          float* __restrict__ qkvn) {
    __shared__ float tile[64][65];
    const int b  = blockIdx.z;
    const int l0 = blockIdx.y * 64, c0 = blockIdx.x * 64;
    const int t  = threadIdx.x;
    #pragma unroll
    for (int u = 0; u < 16; ++u) {
        const int idx = t + 256 * u;
        const int lr = idx >> 6, cr = idx & 63;
        const int c = c0 + cr, g = c >> 5;
        float v = qkv[(size_t)(b * LSEQ + l0 + lr) * C2 + c];
        v = (v - mean[b * 32 + g]) * rstd[b * 32 + g] * scale[c] + bias[c];
        tile[lr][cr] = v;
    }
    __syncthreads();
    #pragma unroll
    for (int u = 0; u < 16; ++u) {
        const int idx = t + 256 * u;
        const int cw = idx >> 6, lw = idx & 63;
        qkvn[(size_t)(b * 1024 + c0 + cw) * LSEQ + l0 + lw] = tile[lw][cw];
    }
}

// ---------------- K4: fused attention with relative position (f32, flash-style) ----------------
__global__ __launch_bounds__(256) void attn_kernel(const float* __restrict__ qkvn,
                                                   const float* __restrict__ rel,
                                                   float* __restrict__ aout) {
    __shared__ float q_s[DQK][BI];
    __shared__ float ki_s[DQK][BI];
    __shared__ float k_s[DQK][BJ];
    __shared__ float v_s[DV][BJ + 1];
    __shared__ float re_s[64][RW];      // S phase: rows 0..31 = re_k(d), 32..63 = re_q(d); PV phase: re_v(dv)
    __shared__ float P_s[BI][BJ + 1];
    __shared__ float m_s[BI], l_s[BI], a_s[BI];

    const int t  = threadIdx.x;
    const int it = blockIdx.x, h = blockIdx.y, b = blockIdx.z;
    const int i0 = it * BI;
    const float* qn = qkvn + (size_t)(b * NH + h) * 128 * LSEQ;

    for (int idx = t; idx < DQK * BI; idx += 256) {
        const int d = idx >> 5, ii = idx & 31;
        q_s[d][ii]  = qn[(size_t)d * LSEQ + i0 + ii];
        ki_s[d][ii] = qn[(size_t)(32 + d) * LSEQ + i0 + ii];
    }
    if (t < BI) { m_s[t] = -__builtin_inff(); l_s[t] = 0.f; }
    __syncthreads();

    const int ri = t >> 3, jt = t & 7;   // S-phase mapping: 32 rows x 8 lanes
    float q_r[DQK], ki_r[DQK];
    #pragma unroll
    for (int d = 0; d < DQK; ++d) { q_r[d] = q_s[d][ri]; ki_r[d] = ki_s[d][ri]; }

    const int dv = t >> 2, ig = t & 3;   // PV mapping: 64 dv x 4 lane-groups
    float O_r[8];
    #pragma unroll
    for (int u = 0; u < 8; ++u) O_r[u] = 0.f;

    for (int j0 = 0; j0 < LSEQ; j0 += BJ) {
        __syncthreads();  // B1: previous PV reads done before overwriting k/v/re
        for (int idx = t; idx < DQK * BJ; idx += 256) {
            const int d = idx >> 6, j = idx & 63;
            k_s[d][j] = qn[(size_t)(32 + d) * LSEQ + j0 + j];
        }
        for (int idx = t; idx < DV * BJ; idx += 256) {
            const int d = idx >> 6, j = idx & 63;
            v_s[d][j] = qn[(size_t)(64 + d) * LSEQ + j0 + j];
        }
        const int r0 = i0 - j0 + 960;   // (i0-j0) + 1023 - (BJ-1); always in [0, 2046-94]
        for (int idx = t; idx < 64 * RW; idx += 256) {
            const int dd = idx / RW, rl = idx % RW;
            const int row = (dd < 32) ? (32 + dd) : (dd - 32);
            re_s[dd][rl] = rel[(size_t)row * RELW + r0 + rl];
        }
        __syncthreads();  // B2

        float p[8];
        float tmax = -__builtin_inff();
        #pragma unroll
        for (int u = 0; u < 8; ++u) {
            const int jj = jt + 8 * u;
            const int rl = ri - jj + (BJ - 1);
            float acc = 0.f;
            #pragma unroll
            for (int d = 0; d < DQK; ++d) {
                acc += q_r[d] * (k_s[d][jj] + re_s[d][rl]);
                acc += ki_r[d] * re_s[32 + d][rl];
            }
            p[u] = acc;
            tmax = fmaxf(tmax, acc);
        }
        #pragma unroll
        for (int o = 1; o < 8; o <<= 1) tmax = fmaxf(tmax, __shfl_xor(tmax, o, 64));
        const float m_old = m_s[ri];
        const float m_new = fmaxf(m_old, tmax);
        float rsum = 0.f;
        #pragma unroll
        for (int u = 0; u < 8; ++u) {
            p[u] = __expf(p[u] - m_new);
            rsum += p[u];
            P_s[ri][jt + 8 * u] = p[u];
        }
        #pragma unroll
        for (int o = 1; o < 8; o <<= 1) rsum += __shfl_xor(rsum, o, 64);
        if (jt == 0) {
            const float al = __expf(m_old - m_new);
            a_s[ri] = al;
            l_s[ri] = l_s[ri] * al + rsum;
            m_s[ri] = m_new;
        }
        __syncthreads();  // B3: P/alpha visible; re_s free for re_v
        for (int idx = t; idx < 64 * RW; idx += 256) {
            const int dd = idx / RW, rl = idx % RW;
            re_s[dd][rl] = rel[(size_t)(64 + dd) * RELW + r0 + rl];
        }
        __syncthreads();  // B4
        #pragma unroll
        for (int u = 0; u < 8; ++u) {
            const int ii = ig + 4 * u;
            float o = O_r[u] * a_s[ii];
            #pragma unroll 8
            for (int j = 0; j < BJ; ++j) {
                o += P_s[ii][j] * (v_s[dv][j] + re_s[dv][ii - j + (BJ - 1)]);
            }
            O_r[u] = o;
        }
    }
    // epilogue: out[b][i0+ii][h*64+dv] = O/l
    #pragma unroll
    for (int u = 0; u < 8; ++u) {
        const int ii = ig + 4 * u;
        aout[((size_t)(b * LSEQ + i0 + ii)) * CIN + h * DV + dv] = O_r[u] / l_s[ii];
    }
}

// ---------------- K6: apply output GN ----------------
__global__ __launch_bounds__(256) void gn_out_apply(const float* __restrict__ aout,
                                                    const float* __restrict__ mean,
                                                    const float* __restrict__ rstd,
                                                    const float* __restrict__ scale,
                                                    const float* __restrict__ bias,
                                                    float* __restrict__ out) {
    const int idx4 = blockIdx.x * 256 + threadIdx.x;   // 524288 float4 total
    const int c = (idx4 & 127) * 4;
    const size_t row = idx4 >> 7;                      // b*1024 + l
    const int b = (int)(row >> 10);
    const int g = c >> 4;
    const float4 v = *reinterpret_cast<const float4*>(&aout[row * 512 + c]);
    const float mu = mean[b * 32 + g], rr = rstd[b * 32 + g];
    const float4 sc = *reinterpret_cast<const float4*>(&scale[c]);
    const float4 bi = *reinterpret_cast<const float4*>(&bias[c]);
    float4 o;
    o.x = (v.x - mu) * rr * sc.x + bi.x;
    o.y = (v.y - mu) * rr * sc.y + bi.y;
    o.z = (v.z - mu) * rr * sc.z + bi.z;
    o.w = (v.w - mu) * rr * sc.w + bi.w;
    *reinterpret_cast<float4*>(&out[row * 512 + c]) = o;
}

extern "C" void kernel_launch(void* const* d_in, const int* in_sizes, int n_in,
                              void* d_out, int out_size, void* d_ws, size_t ws_size,
                              hipStream_t stream) {
    (void)in_sizes; (void)n_in; (void)out_size; (void)ws_size;
    const float* x   = (const float*)d_in[0];
    const float* W   = (const float*)d_in[1];
    const float* gqs = (const float*)d_in[2];
    const float* gqb = (const float*)d_in[3];
    const float* rel = (const float*)d_in[4];
    const float* gos = (const float*)d_in[5];
    const float* gob = (const float*)d_in[6];
    float* out = (float*)d_out;

    char* ws = (char*)d_ws;
    float* qkv   = (float*)ws;                        // 16 MB  [b][l][c2]
    float* qkvn  = (float*)(ws + (16u << 20));        // 16 MB  [b][c2][l]
    float* aoutp = (float*)ws;                        // reuse qkv region (8 MB) [b][l][c]
    float* stats = (float*)(ws + (32u << 20));
    float* meanq = stats,       *rstdq = stats + 128;
    float* meano = stats + 256, *rstdo = stats + 384;

    gemm_qkv<<<dim3(16, 64), 256, 0, stream>>>(x, W, qkv);
    gn_stats<C2, 32><<<dim3(32, BSZ), 256, 0, stream>>>(qkv, meanq, rstdq);
    gn_apply_transpose<<<dim3(16, 16, BSZ), 256, 0, stream>>>(qkv, meanq, rstdq, gqs, gqb, qkvn);
    attn_kernel<<<dim3(LSEQ / BI, NH, BSZ), 256, 0, stream>>>(qkvn, rel, aoutp);
    gn_stats<CIN, 16><<<dim3(32, BSZ), 256, 0, stream>>>(aoutp, meano, rstdo);
    gn_out_apply<<<2048, 256, 0, stream>>>(aoutp, meano, rstdo, gos, gob, out);
}

// Round 3
// 319.648 us; speedup vs baseline: 5.3173x; 5.3173x over previous
//
#include <hip/hip_runtime.h>
#include <hip/hip_bf16.h>

typedef unsigned short ushort;
typedef __attribute__((ext_vector_type(8))) short bf16x8;
typedef __attribute__((ext_vector_type(4))) float f32x4;
typedef __attribute__((ext_vector_type(4))) unsigned short ushort4v;

#define BSZ  4
#define LSEQ 1024
#define CIN  512
#define C2   1024
#define NH   8
#define GEPS 1e-4f
#define BI 64
#define BJ 64

static __device__ __forceinline__ ushort f2b(float f) {
    __hip_bfloat16 h = __float2bfloat16(f);
    return *reinterpret_cast<ushort*>(&h);
}
static __device__ __forceinline__ float b2f(ushort u) {
    __hip_bfloat16 h = *reinterpret_cast<__hip_bfloat16*>(&u);
    return __bfloat162float(h);
}

// ---------------- K1: qkv = x @ W   (M=4096, K=512, N=1024), f32 tiled ----------------
__global__ __launch_bounds__(256) void gemm_qkv(const float* __restrict__ x,
                                                const float* __restrict__ W,
                                                float* __restrict__ qkv) {
    __shared__ float As[16][64];
    __shared__ float Bs[16][64];
    const int t  = threadIdx.x;
    const int tx = t & 15, ty = t >> 4;
    const int m0 = blockIdx.y * 64, n0 = blockIdx.x * 64;
    float acc[4][4] = {};
    for (int k0 = 0; k0 < 512; k0 += 16) {
        {
            const int m = t >> 2, kk = (t & 3) * 4;
            const float4 a = *reinterpret_cast<const float4*>(&x[(size_t)(m0 + m) * 512 + k0 + kk]);
            As[kk + 0][m] = a.x; As[kk + 1][m] = a.y; As[kk + 2][m] = a.z; As[kk + 3][m] = a.w;
            const int kb = t >> 4, n = (t & 15) * 4;
            *reinterpret_cast<float4*>(&Bs[kb][n]) =
                *reinterpret_cast<const float4*>(&W[(size_t)(k0 + kb) * 1024 + n0 + n]);
        }
        __syncthreads();
        #pragma unroll
        for (int k = 0; k < 16; ++k) {
            const float4 a = *reinterpret_cast<const float4*>(&As[k][ty * 4]);
            const float4 b = *reinterpret_cast<const float4*>(&Bs[k][tx * 4]);
            const float av[4] = {a.x, a.y, a.z, a.w};
            const float bv[4] = {b.x, b.y, b.z, b.w};
            #pragma unroll
            for (int i = 0; i < 4; ++i)
                #pragma unroll
                for (int j = 0; j < 4; ++j) acc[i][j] += av[i] * bv[j];
        }
        __syncthreads();
    }
    #pragma unroll
    for (int i = 0; i < 4; ++i) {
        const float4 o = {acc[i][0], acc[i][1], acc[i][2], acc[i][3]};
        *reinterpret_cast<float4*>(&qkv[(size_t)(m0 + ty * 4 + i) * 1024 + n0 + tx * 4]) = o;
    }
}

// ---------------- K2/K7: group-norm stats ----------------
template <int CTOT, int GS>
__global__ __launch_bounds__(256) void gn_stats(const float* __restrict__ xin,
                                                float* __restrict__ mean,
                                                float* __restrict__ rstd) {
    const int g = blockIdx.x, b = blockIdx.y;
    const int t = threadIdx.x;
    const int n = LSEQ * GS;
    float s = 0.f, s2 = 0.f;
    for (int idx = t; idx < n; idx += 256) {
        const int l = idx / GS, c = idx % GS;
        const float v = xin[(size_t)(b * LSEQ + l) * CTOT + g * GS + c];
        s += v; s2 += v * v;
    }
    __shared__ float rs[4], rs2[4];
    #pragma unroll
    for (int o = 32; o; o >>= 1) { s += __shfl_down(s, o, 64); s2 += __shfl_down(s2, o, 64); }
    const int w = t >> 6;
    if ((t & 63) == 0) { rs[w] = s; rs2[w] = s2; }
    __syncthreads();
    if (t == 0) {
        s = rs[0] + rs[1] + rs[2] + rs[3];
        s2 = rs2[0] + rs2[1] + rs2[2] + rs2[3];
        const float mu  = s / n;
        const float var = s2 / n - mu * mu;
        mean[b * 32 + g] = mu;
        rstd[b * 32 + g] = rsqrtf(var + GEPS);
    }
}

// ---------------- K3: apply qkv GN -> bf16 qg[b][l][1024] + lo-residual for q/k + transposed v ----------------
__global__ __launch_bounds__(256) void gn_apply_bf(const float* __restrict__ qkv,
                                                   const float* __restrict__ mean,
                                                   const float* __restrict__ rstd,
                                                   const float* __restrict__ scale,
                                                   const float* __restrict__ bias,
                                                   ushort* __restrict__ qg,
                                                   ushort* __restrict__ qlo,
                                                   ushort* __restrict__ vb) {
    __shared__ float tile[64][65];
    const int b  = blockIdx.z;
    const int l0 = blockIdx.y * 64, c0 = blockIdx.x * 64;
    const int t  = threadIdx.x;
    const bool vhalf = (c0 & 64);
    const int h = c0 >> 7;
    #pragma unroll
    for (int u = 0; u < 16; ++u) {
        const int idx = t + 256 * u;
        const int lr = idx >> 6, cr = idx & 63;
        const int c = c0 + cr, g = c >> 5;
        float v = qkv[(size_t)(b * LSEQ + l0 + lr) * C2 + c];
        v = (v - mean[b * 32 + g]) * rstd[b * 32 + g] * scale[c] + bias[c];
        const ushort hi = f2b(v);
        qg[(size_t)(b * LSEQ + l0 + lr) * C2 + c] = hi;
        if (vhalf) tile[lr][cr] = v;
        else qlo[(size_t)(b * LSEQ + l0 + lr) * 512 + h * 64 + cr] = f2b(v - b2f(hi));
    }
    if (vhalf) {
        __syncthreads();
        #pragma unroll
        for (int u = 0; u < 16; ++u) {
            const int idx = t + 256 * u;
            const int cw = idx >> 6, lw = idx & 63;   // cw = dv
            vb[((size_t)((b * NH + h) * 64 + cw)) * LSEQ + l0 + lw] = f2b(tile[lw][cw]);
        }
    }
}

// ---------------- K4: relT[r][d] = bf16(rel[d^32][r]), r in [0,2048), d in [0,64) ----------------
__global__ __launch_bounds__(256) void prep_relT(const float* __restrict__ rel,
                                                 ushort* __restrict__ relT) {
    __shared__ float tl[64][65];
    const int r0 = blockIdx.x * 64;
    const int t = threadIdx.x;
    #pragma unroll
    for (int u = 0; u < 16; ++u) {
        const int idx = t + 256 * u;
        const int dd = idx >> 6, rr = idx & 63;
        int r = r0 + rr; if (r > 2046) r = 2046;
        tl[dd][rr] = rel[(size_t)(dd ^ 32) * 2047 + r];
    }
    __syncthreads();
    #pragma unroll
    for (int u = 0; u < 16; ++u) {
        const int idx = t + 256 * u;
        const int rr = idx >> 6, dd = idx & 63;
        relT[(size_t)(r0 + rr) * 64 + dd] = f2b(tl[dd][rr]);
    }
}

// ---------------- K5: relV[dv][r] = bf16(rel[64+dv][r]), width padded to 2048 ----------------
__global__ __launch_bounds__(256) void prep_relV(const float* __restrict__ rel,
                                                 ushort* __restrict__ relV) {
    const int idx = blockIdx.x * 256 + threadIdx.x;   // 64*2048
    const int dv = idx >> 11, r = idx & 2047;
    const int rc = r > 2046 ? 2046 : r;
    relV[(size_t)dv * 2048 + r] = f2b(rel[(size_t)(64 + dv) * 2047 + rc]);
}

// ---------------- K6: MFMA flash attention with rpe (skew-GEMM formulation) ----------------
// mfma_f32_16x16x32_bf16; A[m][k] and Bt[n][k] row-major in LDS,
// lane reads row (l&15), 8 contiguous bf16 at col (l>>4)*8 + 32*kstep.
// C/D: col = lane&15, row = (lane>>4)*4 + reg.
// S1 = q.k uses compensated bf16: hi*hi + lo*hi + hi*lo (fp32-grade logits).
__global__ __launch_bounds__(512) void attn_mfma(const ushort* __restrict__ qg,
                                                 const ushort* __restrict__ qlo,
                                                 const ushort* __restrict__ vbuf,
                                                 const ushort* __restrict__ relT,
                                                 const ushort* __restrict__ relV,
                                                 float* __restrict__ aout) {
    __shared__ ushort qi[64][72];     // [ii][d 0..63]  (q: d<32, k_i: d>=32)
    __shared__ ushort qi_lo[64][40];  // [ii][d 0..31]  lo residual of q
    __shared__ ushort kj[64][40];     // [jj][d-32]
    __shared__ ushort kj_lo[64][40];  // [jj][d-32] lo residual
    __shared__ ushort vj[64][72];     // [dv][jj]
    __shared__ ushort rT[128][72];    // [rl][d]   rel[d^32][r0+rl]
    __shared__ ushort rV[64][136];    // [dv][rl]
    __shared__ float  TU[64][130];    // [ii][rl]
    __shared__ float  Ss[64][66];     // [ii][jj]
    __shared__ ushort Ps[64][72];     // [ii][jj] bf16
    __shared__ ushort Pr[64][136];    // [ii][rl] skewed P, zero outside window
    __shared__ float  m_s[64], l_s[64], a_s[64];

    const int t = threadIdx.x;
    const int w = t >> 6, l = t & 63;
    const int lr = l & 15, lq = l >> 4;
    const int i0 = blockIdx.x * BI;
    const int h  = blockIdx.y, b = blockIdx.z;

    const ushort* qrow = qg + (size_t)(b * LSEQ) * C2 + h * 128;
    const ushort* qlrow = qlo + (size_t)(b * LSEQ) * 512 + h * 64;
    const ushort* vsrc = vbuf + (size_t)(b * NH + h) * 64 * LSEQ;

    // stage i-tile (q||k channels, 64 wide) + q lo residual
    #pragma unroll
    for (int u = 0; u < 2; ++u) {
        const int idx = t + 512 * u;
        const int ii = idx >> 4, c4 = (idx & 15) * 4;
        *(ushort4v*)&qi[ii][c4] = *(const ushort4v*)&qrow[(size_t)(i0 + ii) * C2 + c4];
    }
    {
        const int ii = t >> 3, c4 = (t & 7) * 4;
        *(ushort4v*)&qi_lo[ii][c4] = *(const ushort4v*)&qlrow[(size_t)(i0 + ii) * 512 + c4];
    }
    if (t < 64) { m_s[t] = -3.0e38f; l_s[t] = 0.f; }
    for (int idx = t; idx < 64 * 136; idx += 512) Pr[idx / 136][idx % 136] = 0;

    const int mw = w >> 1;      // row-frag of this wave (0..3)
    const int np = w & 1;

    f32x4 Oa[2] = {f32x4{0.f, 0.f, 0.f, 0.f}, f32x4{0.f, 0.f, 0.f, 0.f}};

    __syncthreads();

    for (int j0 = 0; j0 < LSEQ; j0 += BJ) {
        const int r0 = i0 - j0 + 960;   // global r = r0 + rl, rl = ii-jj+63
        // ---- stage j-tile ----
        {
            const int jj = t >> 3, c4 = (t & 7) * 4;
            *(ushort4v*)&kj[jj][c4] = *(const ushort4v*)&qrow[(size_t)(j0 + jj) * C2 + 32 + c4];
            *(ushort4v*)&kj_lo[jj][c4] = *(const ushort4v*)&qlrow[(size_t)(j0 + jj) * 512 + 32 + c4];
            #pragma unroll
            for (int u = 0; u < 2; ++u) {
                const int idx = t + 512 * u;
                const int dv = idx >> 4, c4v = (idx & 15) * 4;
                *(ushort4v*)&vj[dv][c4v] = *(const ushort4v*)&vsrc[(size_t)dv * LSEQ + j0 + c4v];
            }
            #pragma unroll
            for (int u = 0; u < 4; ++u) {
                const int idx = t + 512 * u;
                const int rl = idx >> 4, c4r = (idx & 15) * 4;
                *(ushort4v*)&rT[rl][c4r] = *(const ushort4v*)&relT[(size_t)(r0 + rl) * 64 + c4r];
            }
            #pragma unroll
            for (int u = 0; u < 4; ++u) {
                const int idx = t + 512 * u;
                const int dv = idx >> 5, c4r = (idx & 31) * 4;
                *(ushort4v*)&rV[dv][c4r] = *(const ushort4v*)&relV[(size_t)dv * 2048 + r0 + c4r];
            }
        }
        __syncthreads();

        // ---- TU GEMM: [64 ii] x [128 rl], K=64 ----
        {
            const bf16x8 a0 = *(const bf16x8*)&qi[16 * mw + lr][8 * lq];
            const bf16x8 a1 = *(const bf16x8*)&qi[16 * mw + lr][8 * lq + 32];
            #pragma unroll
            for (int nn = 0; nn < 4; ++nn) {
                const int n = 4 * np + nn;
                f32x4 acc = {0.f, 0.f, 0.f, 0.f};
                const bf16x8 b0 = *(const bf16x8*)&rT[16 * n + lr][8 * lq];
                acc = __builtin_amdgcn_mfma_f32_16x16x32_bf16(a0, b0, acc, 0, 0, 0);
                const bf16x8 b1 = *(const bf16x8*)&rT[16 * n + lr][8 * lq + 32];
                acc = __builtin_amdgcn_mfma_f32_16x16x32_bf16(a1, b1, acc, 0, 0, 0);
                #pragma unroll
                for (int e = 0; e < 4; ++e) TU[16 * mw + 4 * lq + e][16 * n + lr] = acc[e];
            }
        }
        __syncthreads();

        // ---- S1 GEMM (K=32, q channels, compensated bf16) + TU skew-gather -> Ss ----
        {
            const bf16x8 a_hi = *(const bf16x8*)&qi[16 * mw + lr][8 * lq];
            const bf16x8 a_lo = *(const bf16x8*)&qi_lo[16 * mw + lr][8 * lq];
            #pragma unroll
            for (int nn = 0; nn < 2; ++nn) {
                const int n = 2 * np + nn;
                f32x4 acc = {0.f, 0.f, 0.f, 0.f};
                const bf16x8 b_hi = *(const bf16x8*)&kj[16 * n + lr][8 * lq];
                const bf16x8 b_lo = *(const bf16x8*)&kj_lo[16 * n + lr][8 * lq];
                acc = __builtin_amdgcn_mfma_f32_16x16x32_bf16(a_hi, b_lo, acc, 0, 0, 0);
                acc = __builtin_amdgcn_mfma_f32_16x16x32_bf16(a_lo, b_hi, acc, 0, 0, 0);
                acc = __builtin_amdgcn_mfma_f32_16x16x32_bf16(a_hi, b_hi, acc, 0, 0, 0);
                #pragma unroll
                for (int e = 0; e < 4; ++e) {
                    const int row = 16 * mw + 4 * lq + e, col = 16 * n + lr;
                    Ss[row][col] = acc[e] + TU[row][row - col + 63];
                }
            }
        }
        __syncthreads();

        // ---- online softmax over Ss rows ----
        {
            const int row = t >> 3, s8 = t & 7;
            float pv[8];
            float mx = -3.0e38f;
            #pragma unroll
            for (int e = 0; e < 8; ++e) { pv[e] = Ss[row][8 * s8 + e]; mx = fmaxf(mx, pv[e]); }
            mx = fmaxf(mx, __shfl_xor(mx, 1, 64));
            mx = fmaxf(mx, __shfl_xor(mx, 2, 64));
            mx = fmaxf(mx, __shfl_xor(mx, 4, 64));
            const float mo = m_s[row];
            const float mn = fmaxf(mo, mx);
            float sum = 0.f;
            #pragma unroll
            for (int e = 0; e < 8; ++e) {
                const float p = __expf(pv[e] - mn);
                sum += p;
                const int jj = 8 * s8 + e;
                const ushort pb = f2b(p);
                Ps[row][jj] = pb;
                Pr[row][row - jj + 63] = pb;
            }
            sum += __shfl_xor(sum, 1, 64);
            sum += __shfl_xor(sum, 2, 64);
            sum += __shfl_xor(sum, 4, 64);
            if (s8 == 0) {
                a_s[row] = __expf(mo - mn);
                l_s[row] = l_s[row] * a_s[row] + sum;
                m_s[row] = mn;
            }
        }
        __syncthreads();

        // ---- PV: O = diag(a)*O + P*v + Prl*rV ----
        {
            float al[4];
            #pragma unroll
            for (int e = 0; e < 4; ++e) al[e] = a_s[16 * mw + 4 * lq + e];
            bf16x8 pa[2], pra[4];
            #pragma unroll
            for (int kk = 0; kk < 2; ++kk) pa[kk] = *(const bf16x8*)&Ps[16 * mw + lr][8 * lq + 32 * kk];
            #pragma unroll
            for (int kk = 0; kk < 4; ++kk) pra[kk] = *(const bf16x8*)&Pr[16 * mw + lr][8 * lq + 32 * kk];
            #pragma unroll
            for (int nn = 0; nn < 2; ++nn) {
                const int n = 2 * np + nn;
                f32x4 acc = Oa[nn];
                #pragma unroll
                for (int e = 0; e < 4; ++e) acc[e] *= al[e];
                #pragma unroll
                for (int kk = 0; kk < 2; ++kk) {
                    const bf16x8 bv = *(const bf16x8*)&vj[16 * n + lr][8 * lq + 32 * kk];
                    acc = __builtin_amdgcn_mfma_f32_16x16x32_bf16(pa[kk], bv, acc, 0, 0, 0);
                }
                #pragma unroll
                for (int kk = 0; kk < 4; ++kk) {
                    const bf16x8 br = *(const bf16x8*)&rV[16 * n + lr][8 * lq + 32 * kk];
                    acc = __builtin_amdgcn_mfma_f32_16x16x32_bf16(pra[kk], br, acc, 0, 0, 0);
                }
                Oa[nn] = acc;
            }
        }
        __syncthreads();
    }

    // ---- epilogue: aout[b][i][h*64+dv] = O / l ----
    #pragma unroll
    for (int nn = 0; nn < 2; ++nn) {
        const int n = 2 * np + nn;
        #pragma unroll
        for (int e = 0; e < 4; ++e) {
            const int row = 16 * mw + 4 * lq + e, dv = 16 * n + lr;
            aout[((size_t)(b * LSEQ + i0 + row)) * CIN + h * 64 + dv] = Oa[nn][e] / l_s[row];
        }
    }
}

// ---------------- K8: apply output GN ----------------
__global__ __launch_bounds__(256) void gn_out_apply(const float* __restrict__ aout,
                                                    const float* __restrict__ mean,
                                                    const float* __restrict__ rstd,
                                                    const float* __restrict__ scale,
                                                    const float* __restrict__ bias,
                                                    float* __restrict__ out) {
    const int idx4 = blockIdx.x * 256 + threadIdx.x;
    const int c = (idx4 & 127) * 4;
    const size_t row = idx4 >> 7;
    const int b = (int)(row >> 10);
    const int g = c >> 4;
    const float4 v = *reinterpret_cast<const float4*>(&aout[row * 512 + c]);
    const float mu = mean[b * 32 + g], rr = rstd[b * 32 + g];
    const float4 sc = *reinterpret_cast<const float4*>(&scale[c]);
    const float4 bi = *reinterpret_cast<const float4*>(&bias[c]);
    float4 o;
    o.x = (v.x - mu) * rr * sc.x + bi.x;
    o.y = (v.y - mu) * rr * sc.y + bi.y;
    o.z = (v.z - mu) * rr * sc.z + bi.z;
    o.w = (v.w - mu) * rr * sc.w + bi.w;
    *reinterpret_cast<float4*>(&out[row * 512 + c]) = o;
}

extern "C" void kernel_launch(void* const* d_in, const int* in_sizes, int n_in,
                              void* d_out, int out_size, void* d_ws, size_t ws_size,
                              hipStream_t stream) {
    (void)in_sizes; (void)n_in; (void)out_size; (void)ws_size;
    const float* x   = (const float*)d_in[0];
    const float* W   = (const float*)d_in[1];
    const float* gqs = (const float*)d_in[2];
    const float* gqb = (const float*)d_in[3];
    const float* rel = (const float*)d_in[4];
    const float* gos = (const float*)d_in[5];
    const float* gob = (const float*)d_in[6];
    float* out = (float*)d_out;

    char* ws = (char*)d_ws;
    float*  qkv  = (float*)ws;                                  // 16 MB [b][l][c2] f32
    ushort* qg   = (ushort*)(ws + (16u << 20));                 //  8 MB [b][l][c2] bf16
    ushort* vb   = (ushort*)(ws + (24u << 20));                 //  4 MB [b][h][dv][l] bf16
    ushort* rTb  = (ushort*)(ws + (28u << 20));                 // 256 KB
    ushort* rVb  = (ushort*)(ws + (28u << 20) + (256u << 10));  // 256 KB
    ushort* qlo  = (ushort*)(ws + (28u << 20) + (512u << 10));  //  4 MB [b][l][h*64] bf16 lo-residual
    float*  aout = (float*)ws;                                  // reuse (8 MB) [b][l][c] f32
    float*  stats = (float*)(ws + (32u << 20) + (512u << 10));
    float* meanq = stats,       *rstdq = stats + 128;
    float* meano = stats + 256, *rstdo = stats + 384;

    gemm_qkv<<<dim3(16, 64), 256, 0, stream>>>(x, W, qkv);
    gn_stats<C2, 32><<<dim3(32, BSZ), 256, 0, stream>>>(qkv, meanq, rstdq);
    gn_apply_bf<<<dim3(16, 16, BSZ), 256, 0, stream>>>(qkv, meanq, rstdq, gqs, gqb, qg, qlo, vb);
    prep_relT<<<32, 256, 0, stream>>>(rel, rTb);
    prep_relV<<<512, 256, 0, stream>>>(rel, rVb);
    attn_mfma<<<dim3(LSEQ / BI, NH, BSZ), 512, 0, stream>>>(qg, qlo, vb, rTb, rVb, aout);
    gn_stats<CIN, 16><<<dim3(32, BSZ), 256, 0, stream>>>(aout, meano, rstdo);
    gn_out_apply<<<2048, 256, 0, stream>>>(aout, meano, rstdo, gos, gob, out);
}

// Round 4
// 300.916 us; speedup vs baseline: 5.6483x; 1.0622x over previous
//
#include <hip/hip_runtime.h>
#include <hip/hip_bf16.h>

typedef unsigned short ushort;
typedef __attribute__((ext_vector_type(8))) short bf16x8;
typedef __attribute__((ext_vector_type(4))) float f32x4;
typedef __attribute__((ext_vector_type(4))) unsigned short ushort4v;

#define BSZ  4
#define LSEQ 1024
#define CIN  512
#define C2   1024
#define NH   8
#define GEPS 1e-4f
#define BI 64
#define BJ 64

static __device__ __forceinline__ ushort f2b(float f) {
    __hip_bfloat16 h = __float2bfloat16(f);
    return *reinterpret_cast<ushort*>(&h);
}
static __device__ __forceinline__ float b2f(ushort u) {
    __hip_bfloat16 h = *reinterpret_cast<__hip_bfloat16*>(&u);
    return __bfloat162float(h);
}

// ---------------- P1: split x into hi/lo bf16 ----------------
__global__ __launch_bounds__(256) void prep_xsplit(const float* __restrict__ x,
                                                   ushort* __restrict__ xh,
                                                   ushort* __restrict__ xl) {
    const size_t i4 = (size_t)blockIdx.x * 256 + threadIdx.x;   // 2M/4 threads
    const float4 v = *reinterpret_cast<const float4*>(&x[i4 * 4]);
    ushort4v h, lo;
    const float vv[4] = {v.x, v.y, v.z, v.w};
    #pragma unroll
    for (int c = 0; c < 4; ++c) {
        const ushort hh = f2b(vv[c]);
        h[c] = hh;
        lo[c] = f2b(vv[c] - b2f(hh));
    }
    *reinterpret_cast<ushort4v*>(&xh[i4 * 4]) = h;
    *reinterpret_cast<ushort4v*>(&xl[i4 * 4]) = lo;
}

// ---------------- P2: W [512][1024] -> WT hi/lo bf16 [1024][512] ----------------
__global__ __launch_bounds__(256) void prep_wT(const float* __restrict__ W,
                                               ushort* __restrict__ wth,
                                               ushort* __restrict__ wtl) {
    __shared__ float tl[64][65];
    const int k0 = blockIdx.y * 64, n0 = blockIdx.x * 64;
    const int t = threadIdx.x;
    #pragma unroll
    for (int u = 0; u < 16; ++u) {
        const int idx = t + 256 * u;
        const int kk = idx >> 6, nn = idx & 63;
        tl[kk][nn] = W[(size_t)(k0 + kk) * 1024 + n0 + nn];
    }
    __syncthreads();
    #pragma unroll
    for (int u = 0; u < 16; ++u) {
        const int idx = t + 256 * u;
        const int nn = idx >> 6, kk = idx & 63;
        const float v = tl[kk][nn];
        const ushort h = f2b(v);
        wth[(size_t)(n0 + nn) * 512 + k0 + kk] = h;
        wtl[(size_t)(n0 + nn) * 512 + k0 + kk] = f2b(v - b2f(h));
    }
}

// ---------------- K1: qkv = x @ W via split-bf16 MFMA (3 products) ----------------
__global__ __launch_bounds__(256) void gemm_qkv_mfma(const ushort* __restrict__ xh,
                                                     const ushort* __restrict__ xl,
                                                     const ushort* __restrict__ wth,
                                                     const ushort* __restrict__ wtl,
                                                     float* __restrict__ qkv) {
    __shared__ ushort Ah[128][40];
    __shared__ ushort Al[128][40];
    __shared__ ushort Bh[128][40];
    __shared__ ushort Bl[128][40];
    const int t = threadIdx.x;
    const int w = t >> 6, l = t & 63;
    const int lr = l & 15, lq = l >> 4;
    const int wm = w >> 1, wn = w & 1;
    const int m0 = blockIdx.y * 128, n0 = blockIdx.x * 128;
    f32x4 acc[4][4] = {};
    for (int k0 = 0; k0 < 512; k0 += 32) {
        __syncthreads();
        #pragma unroll
        for (int u = 0; u < 2; ++u) {
            const int idx = t + 256 * u;
            const int r = idx >> 2, c16 = (idx & 3) * 8;
            *(bf16x8*)&Ah[r][c16] = *(const bf16x8*)&xh[(size_t)(m0 + r) * 512 + k0 + c16];
            *(bf16x8*)&Al[r][c16] = *(const bf16x8*)&xl[(size_t)(m0 + r) * 512 + k0 + c16];
            *(bf16x8*)&Bh[r][c16] = *(const bf16x8*)&wth[(size_t)(n0 + r) * 512 + k0 + c16];
            *(bf16x8*)&Bl[r][c16] = *(const bf16x8*)&wtl[(size_t)(n0 + r) * 512 + k0 + c16];
        }
        __syncthreads();
        bf16x8 ah[4], av[4];
        #pragma unroll
        for (int mi = 0; mi < 4; ++mi) {
            ah[mi] = *(const bf16x8*)&Ah[64 * wm + 16 * mi + lr][8 * lq];
            av[mi] = *(const bf16x8*)&Al[64 * wm + 16 * mi + lr][8 * lq];
        }
        #pragma unroll
        for (int ni = 0; ni < 4; ++ni) {
            const bf16x8 bh = *(const bf16x8*)&Bh[64 * wn + 16 * ni + lr][8 * lq];
            const bf16x8 bl = *(const bf16x8*)&Bl[64 * wn + 16 * ni + lr][8 * lq];
            #pragma unroll
            for (int mi = 0; mi < 4; ++mi) {
                f32x4 a = acc[mi][ni];
                a = __builtin_amdgcn_mfma_f32_16x16x32_bf16(ah[mi], bl, a, 0, 0, 0);
                a = __builtin_amdgcn_mfma_f32_16x16x32_bf16(av[mi], bh, a, 0, 0, 0);
                a = __builtin_amdgcn_mfma_f32_16x16x32_bf16(ah[mi], bh, a, 0, 0, 0);
                acc[mi][ni] = a;
            }
        }
    }
    #pragma unroll
    for (int mi = 0; mi < 4; ++mi)
        #pragma unroll
        for (int ni = 0; ni < 4; ++ni)
            #pragma unroll
            for (int e = 0; e < 4; ++e)
                qkv[(size_t)(m0 + 64 * wm + 16 * mi + 4 * lq + e) * 1024 + n0 + 64 * wn + 16 * ni + lr] = acc[mi][ni][e];
}

// ---------------- K2/K7: group-norm stats ----------------
template <int CTOT, int GS>
__global__ __launch_bounds__(256) void gn_stats(const float* __restrict__ xin,
                                                float* __restrict__ mean,
                                                float* __restrict__ rstd) {
    const int g = blockIdx.x, b = blockIdx.y;
    const int t = threadIdx.x;
    const int n = LSEQ * GS;
    float s = 0.f, s2 = 0.f;
    for (int idx = t; idx < n; idx += 256) {
        const int l = idx / GS, c = idx % GS;
        const float v = xin[(size_t)(b * LSEQ + l) * CTOT + g * GS + c];
        s += v; s2 += v * v;
    }
    __shared__ float rs[4], rs2[4];
    #pragma unroll
    for (int o = 32; o; o >>= 1) { s += __shfl_down(s, o, 64); s2 += __shfl_down(s2, o, 64); }
    const int w = t >> 6;
    if ((t & 63) == 0) { rs[w] = s; rs2[w] = s2; }
    __syncthreads();
    if (t == 0) {
        s = rs[0] + rs[1] + rs[2] + rs[3];
        s2 = rs2[0] + rs2[1] + rs2[2] + rs2[3];
        const float mu  = s / n;
        const float var = s2 / n - mu * mu;
        mean[b * 32 + g] = mu;
        rstd[b * 32 + g] = rsqrtf(var + GEPS);
    }
}

// ---------------- K3: apply qkv GN -> bf16 qg + lo-residual (q/k) + transposed v ----------------
__global__ __launch_bounds__(256) void gn_apply_bf(const float* __restrict__ qkv,
                                                   const float* __restrict__ mean,
                                                   const float* __restrict__ rstd,
                                                   const float* __restrict__ scale,
                                                   const float* __restrict__ bias,
                                                   ushort* __restrict__ qg,
                                                   ushort* __restrict__ qlo,
                                                   ushort* __restrict__ vb) {
    __shared__ float tile[64][65];
    const int b  = blockIdx.z;
    const int l0 = blockIdx.y * 64, c0 = blockIdx.x * 64;
    const int t  = threadIdx.x;
    const bool vhalf = (c0 & 64);
    const int h = c0 >> 7;
    #pragma unroll
    for (int u = 0; u < 16; ++u) {
        const int idx = t + 256 * u;
        const int lr = idx >> 6, cr = idx & 63;
        const int c = c0 + cr, g = c >> 5;
        float v = qkv[(size_t)(b * LSEQ + l0 + lr) * C2 + c];
        v = (v - mean[b * 32 + g]) * rstd[b * 32 + g] * scale[c] + bias[c];
        const ushort hi = f2b(v);
        qg[(size_t)(b * LSEQ + l0 + lr) * C2 + c] = hi;
        if (vhalf) tile[lr][cr] = v;
        else qlo[(size_t)(b * LSEQ + l0 + lr) * 512 + h * 64 + cr] = f2b(v - b2f(hi));
    }
    if (vhalf) {
        __syncthreads();
        #pragma unroll
        for (int u = 0; u < 16; ++u) {
            const int idx = t + 256 * u;
            const int cw = idx >> 6, lw = idx & 63;   // cw = dv
            vb[((size_t)((b * NH + h) * 64 + cw)) * LSEQ + l0 + lw] = f2b(tile[lw][cw]);
        }
    }
}

// ---------------- K4: relT[r][d] = bf16(rel[d^32][r]) ----------------
__global__ __launch_bounds__(256) void prep_relT(const float* __restrict__ rel,
                                                 ushort* __restrict__ relT) {
    __shared__ float tl[64][65];
    const int r0 = blockIdx.x * 64;
    const int t = threadIdx.x;
    #pragma unroll
    for (int u = 0; u < 16; ++u) {
        const int idx = t + 256 * u;
        const int dd = idx >> 6, rr = idx & 63;
        int r = r0 + rr; if (r > 2046) r = 2046;
        tl[dd][rr] = rel[(size_t)(dd ^ 32) * 2047 + r];
    }
    __syncthreads();
    #pragma unroll
    for (int u = 0; u < 16; ++u) {
        const int idx = t + 256 * u;
        const int rr = idx >> 6, dd = idx & 63;
        relT[(size_t)(r0 + rr) * 64 + dd] = f2b(tl[dd][rr]);
    }
}

// ---------------- K5: relV[dv][r] = bf16(rel[64+dv][r]) ----------------
__global__ __launch_bounds__(256) void prep_relV(const float* __restrict__ rel,
                                                 ushort* __restrict__ relV) {
    const int idx = blockIdx.x * 256 + threadIdx.x;   // 64*2048
    const int dv = idx >> 11, r = idx & 2047;
    const int rc = r > 2046 ? 2046 : r;
    relV[(size_t)dv * 2048 + r] = f2b(rel[(size_t)(64 + dv) * 2047 + rc]);
}

// ---------------- K6: MFMA flash attention, in-register softmax, banded TU ----------------
// mfma_f32_16x16x32_bf16; A[m][k], Bt[n][k] row-major in LDS; lane reads row (l&15),
// 8 contiguous bf16 at (l>>4)*8 (+32 per kstep). C/D: col=lane&15, row=(lane>>4)*4+reg.
__global__ __launch_bounds__(512) void attn_mfma(const ushort* __restrict__ qg,
                                                 const ushort* __restrict__ qlo,
                                                 const ushort* __restrict__ vbuf,
                                                 const ushort* __restrict__ relT,
                                                 const ushort* __restrict__ relV,
                                                 float* __restrict__ aout) {
    __shared__ ushort qi[64][72];     // [ii][d 0..63] (q: d<32, k_i: d>=32)
    __shared__ ushort qi_lo[64][40];  // [ii][d 0..31] lo residual of q
    __shared__ ushort kj[64][40];     // [jj][d-32]
    __shared__ ushort kj_lo[64][40];
    __shared__ ushort vj[64][72];     // [dv][jj]
    __shared__ ushort rT[128][72];    // [rl][d]
    __shared__ ushort rV[64][136];    // [dv][rl]
    __shared__ ushort TUb[64][136];   // [ii][rl] bf16, band rl in [16mw, 16mw+79]
    __shared__ ushort Ps[64][72];     // [ii][jj]
    __shared__ ushort Pr[64][136];    // [ii][rl] skewed P, zero outside [row,row+63]
    __shared__ float  pmax[2][64];
    __shared__ float  psum[2][64];

    const int t = threadIdx.x;
    const int w = t >> 6, l = t & 63;
    const int lr = l & 15, lq = l >> 4;
    const int mw = w >> 1, np = w & 1;
    const int i0 = blockIdx.x * BI;
    const int h  = blockIdx.y, b = blockIdx.z;

    const ushort* qrow  = qg  + (size_t)(b * LSEQ) * C2 + h * 128;
    const ushort* qlrow = qlo + (size_t)(b * LSEQ) * 512 + h * 64;
    const ushort* vsrc  = vbuf + (size_t)(b * NH + h) * 64 * LSEQ;

    #pragma unroll
    for (int u = 0; u < 2; ++u) {
        const int idx = t + 512 * u;
        const int ii = idx >> 4, c4 = (idx & 15) * 4;
        *(ushort4v*)&qi[ii][c4] = *(const ushort4v*)&qrow[(size_t)(i0 + ii) * C2 + c4];
    }
    {
        const int ii = t >> 3, c4 = (t & 7) * 4;
        *(ushort4v*)&qi_lo[ii][c4] = *(const ushort4v*)&qlrow[(size_t)(i0 + ii) * 512 + c4];
    }
    for (int idx = t; idx < 64 * 136; idx += 512) Pr[idx / 136][idx % 136] = 0;

    float m_r[4], l_r[4];
    #pragma unroll
    for (int e = 0; e < 4; ++e) { m_r[e] = -3.0e38f; l_r[e] = 0.f; }
    f32x4 Oa[2] = {f32x4{0.f, 0.f, 0.f, 0.f}, f32x4{0.f, 0.f, 0.f, 0.f}};

    __syncthreads();

    for (int j0 = 0; j0 < LSEQ; j0 += BJ) {
        const int r0 = i0 - j0 + 960;
        __syncthreads();  // B1: prev iter's reads done before restaging
        {
            const int jj = t >> 3, c4 = (t & 7) * 4;
            *(ushort4v*)&kj[jj][c4]    = *(const ushort4v*)&qrow[(size_t)(j0 + jj) * C2 + 32 + c4];
            *(ushort4v*)&kj_lo[jj][c4] = *(const ushort4v*)&qlrow[(size_t)(j0 + jj) * 512 + 32 + c4];
            #pragma unroll
            for (int u = 0; u < 2; ++u) {
                const int idx = t + 512 * u;
                const int dv = idx >> 4, c4v = (idx & 15) * 4;
                *(ushort4v*)&vj[dv][c4v] = *(const ushort4v*)&vsrc[(size_t)dv * LSEQ + j0 + c4v];
            }
            #pragma unroll
            for (int u = 0; u < 4; ++u) {
                const int idx = t + 512 * u;
                const int rl = idx >> 4, c4r = (idx & 15) * 4;
                *(ushort4v*)&rT[rl][c4r] = *(const ushort4v*)&relT[(size_t)(r0 + rl) * 64 + c4r];
            }
            #pragma unroll
            for (int u = 0; u < 4; ++u) {
                const int idx = t + 512 * u;
                const int dv = idx >> 5, c4r = (idx & 31) * 4;
                *(ushort4v*)&rV[dv][c4r] = *(const ushort4v*)&relV[(size_t)dv * 2048 + r0 + c4r];
            }
        }
        __syncthreads();  // B2

        // ---- TU band: tiles (mw, ct), ct in [mw, mw+4]; np=0 gets 3, np=1 gets 2 ----
        {
            const bf16x8 a0 = *(const bf16x8*)&qi[16 * mw + lr][8 * lq];
            const bf16x8 a1 = *(const bf16x8*)&qi[16 * mw + lr][8 * lq + 32];
            const int cbase = mw + (np ? 3 : 0);
            const int nct = np ? 2 : 3;
            for (int c = 0; c < nct; ++c) {
                const int ct = cbase + c;
                f32x4 acc = {0.f, 0.f, 0.f, 0.f};
                const bf16x8 b0 = *(const bf16x8*)&rT[16 * ct + lr][8 * lq];
                acc = __builtin_amdgcn_mfma_f32_16x16x32_bf16(a0, b0, acc, 0, 0, 0);
                const bf16x8 b1 = *(const bf16x8*)&rT[16 * ct + lr][8 * lq + 32];
                acc = __builtin_amdgcn_mfma_f32_16x16x32_bf16(a1, b1, acc, 0, 0, 0);
                #pragma unroll
                for (int e = 0; e < 4; ++e) TUb[16 * mw + 4 * lq + e][16 * ct + lr] = f2b(acc[e]);
            }
        }
        __syncthreads();  // B3

        // ---- S1 (compensated bf16) + TU skew-gather, kept in registers ----
        f32x4 sv[2];
        {
            const bf16x8 a_hi = *(const bf16x8*)&qi[16 * mw + lr][8 * lq];
            const bf16x8 a_lo = *(const bf16x8*)&qi_lo[16 * mw + lr][8 * lq];
            #pragma unroll
            for (int nn = 0; nn < 2; ++nn) {
                const int n = 2 * np + nn;
                f32x4 acc = {0.f, 0.f, 0.f, 0.f};
                const bf16x8 b_hi = *(const bf16x8*)&kj[16 * n + lr][8 * lq];
                const bf16x8 b_lo = *(const bf16x8*)&kj_lo[16 * n + lr][8 * lq];
                acc = __builtin_amdgcn_mfma_f32_16x16x32_bf16(a_hi, b_lo, acc, 0, 0, 0);
                acc = __builtin_amdgcn_mfma_f32_16x16x32_bf16(a_lo, b_hi, acc, 0, 0, 0);
                acc = __builtin_amdgcn_mfma_f32_16x16x32_bf16(a_hi, b_hi, acc, 0, 0, 0);
                #pragma unroll
                for (int e = 0; e < 4; ++e) {
                    const int row = 16 * mw + 4 * lq + e, col = 16 * n + lr;
                    acc[e] += b2f(TUb[row][row - col + 63]);
                }
                sv[nn] = acc;
            }
        }
        // row max: reduce over 16 lr lanes, then cross-np via LDS
        float mx[4];
        #pragma unroll
        for (int e = 0; e < 4; ++e) mx[e] = fmaxf(sv[0][e], sv[1][e]);
        #pragma unroll
        for (int o = 1; o < 16; o <<= 1)
            #pragma unroll
            for (int e = 0; e < 4; ++e) mx[e] = fmaxf(mx[e], __shfl_xor(mx[e], o, 64));
        if (lr == 0)
            #pragma unroll
            for (int e = 0; e < 4; ++e) pmax[np][16 * mw + 4 * lq + e] = mx[e];
        __syncthreads();  // B4

        float alpha[4], mn[4], ssum[4];
        #pragma unroll
        for (int e = 0; e < 4; ++e) {
            const int row = 16 * mw + 4 * lq + e;
            mn[e] = fmaxf(fmaxf(pmax[0][row], pmax[1][row]), m_r[e]);
            alpha[e] = __expf(m_r[e] - mn[e]);
            m_r[e] = mn[e];
            ssum[e] = 0.f;
        }
        #pragma unroll
        for (int nn = 0; nn < 2; ++nn)
            #pragma unroll
            for (int e = 0; e < 4; ++e) {
                const float p = __expf(sv[nn][e] - mn[e]);
                ssum[e] += p;
                const ushort pb = f2b(p);
                const int row = 16 * mw + 4 * lq + e, col = 16 * (2 * np + nn) + lr;
                Ps[row][col] = pb;
                Pr[row][row - col + 63] = pb;
            }
        #pragma unroll
        for (int o = 1; o < 16; o <<= 1)
            #pragma unroll
            for (int e = 0; e < 4; ++e) ssum[e] += __shfl_xor(ssum[e], o, 64);
        if (lr == 0)
            #pragma unroll
            for (int e = 0; e < 4; ++e) psum[np][16 * mw + 4 * lq + e] = ssum[e];
        __syncthreads();  // B5

        #pragma unroll
        for (int e = 0; e < 4; ++e) {
            const int row = 16 * mw + 4 * lq + e;
            l_r[e] = l_r[e] * alpha[e] + psum[0][row] + psum[1][row];
        }
        // ---- PV: O = diag(alpha)*O + P*v + Pr*rV ----
        {
            bf16x8 pa[2], pra[4];
            #pragma unroll
            for (int kk = 0; kk < 2; ++kk) pa[kk] = *(const bf16x8*)&Ps[16 * mw + lr][8 * lq + 32 * kk];
            #pragma unroll
            for (int kk = 0; kk < 4; ++kk) pra[kk] = *(const bf16x8*)&Pr[16 * mw + lr][8 * lq + 32 * kk];
            #pragma unroll
            for (int nn = 0; nn < 2; ++nn) {
                const int n = 2 * np + nn;
                f32x4 acc = Oa[nn];
                #pragma unroll
                for (int e = 0; e < 4; ++e) acc[e] *= alpha[e];
                #pragma unroll
                for (int kk = 0; kk < 2; ++kk) {
                    const bf16x8 bv = *(const bf16x8*)&vj[16 * n + lr][8 * lq + 32 * kk];
                    acc = __builtin_amdgcn_mfma_f32_16x16x32_bf16(pa[kk], bv, acc, 0, 0, 0);
                }
                #pragma unroll
                for (int kk = 0; kk < 4; ++kk) {
                    const bf16x8 br = *(const bf16x8*)&rV[16 * n + lr][8 * lq + 32 * kk];
                    acc = __builtin_amdgcn_mfma_f32_16x16x32_bf16(pra[kk], br, acc, 0, 0, 0);
                }
                Oa[nn] = acc;
            }
        }
    }

    #pragma unroll
    for (int nn = 0; nn < 2; ++nn) {
        const int n = 2 * np + nn;
        #pragma unroll
        for (int e = 0; e < 4; ++e) {
            const int row = 16 * mw + 4 * lq + e, dv = 16 * n + lr;
            aout[((size_t)(b * LSEQ + i0 + row)) * CIN + h * 64 + dv] = Oa[nn][e] / l_r[e];
        }
    }
}

// ---------------- K8: apply output GN ----------------
__global__ __launch_bounds__(256) void gn_out_apply(const float* __restrict__ aout,
                                                    const float* __restrict__ mean,
                                                    const float* __restrict__ rstd,
                                                    const float* __restrict__ scale,
                                                    const float* __restrict__ bias,
                                                    float* __restrict__ out) {
    const int idx4 = blockIdx.x * 256 + threadIdx.x;
    const int c = (idx4 & 127) * 4;
    const size_t row = idx4 >> 7;
    const int b = (int)(row >> 10);
    const int g = c >> 4;
    const float4 v = *reinterpret_cast<const float4*>(&aout[row * 512 + c]);
    const float mu = mean[b * 32 + g], rr = rstd[b * 32 + g];
    const float4 sc = *reinterpret_cast<const float4*>(&scale[c]);
    const float4 bi = *reinterpret_cast<const float4*>(&bias[c]);
    float4 o;
    o.x = (v.x - mu) * rr * sc.x + bi.x;
    o.y = (v.y - mu) * rr * sc.y + bi.y;
    o.z = (v.z - mu) * rr * sc.z + bi.z;
    o.w = (v.w - mu) * rr * sc.w + bi.w;
    *reinterpret_cast<float4*>(&out[row * 512 + c]) = o;
}

extern "C" void kernel_launch(void* const* d_in, const int* in_sizes, int n_in,
                              void* d_out, int out_size, void* d_ws, size_t ws_size,
                              hipStream_t stream) {
    (void)in_sizes; (void)n_in; (void)out_size; (void)ws_size;
    const float* x   = (const float*)d_in[0];
    const float* W   = (const float*)d_in[1];
    const float* gqs = (const float*)d_in[2];
    const float* gqb = (const float*)d_in[3];
    const float* rel = (const float*)d_in[4];
    const float* gos = (const float*)d_in[5];
    const float* gob = (const float*)d_in[6];
    float* out = (float*)d_out;

    char* ws = (char*)d_ws;
    float*  qkv  = (float*)ws;                                  // 16 MB [b][l][c2] f32
    ushort* qg   = (ushort*)(ws + (16u << 20));                 //  8 MB [b][l][c2] bf16
    ushort* vb   = (ushort*)(ws + (24u << 20));                 //  4 MB [b][h][dv][l]
    ushort* rTb  = (ushort*)(ws + (28u << 20));                 // 256 KB
    ushort* rVb  = (ushort*)(ws + (28u << 20) + (256u << 10));  // 256 KB
    ushort* qlo  = (ushort*)(ws + (28u << 20) + (512u << 10));  //  4 MB [b][l][h*64]
    float*  aout = (float*)ws;                                  // reuse qkv region
    float*  stats = (float*)(ws + (32u << 20) + (512u << 10));
    float* meanq = stats,       *rstdq = stats + 128;
    float* meano = stats + 256, *rstdo = stats + 384;
    // transient (dead after gemm): alias the qg/vb regions
    ushort* xhi = (ushort*)(ws + (16u << 20));                  // 4 MB
    ushort* xlo = (ushort*)(ws + (20u << 20));                  // 4 MB
    ushort* wth = (ushort*)(ws + (24u << 20));                  // 1 MB
    ushort* wtl = (ushort*)(ws + (25u << 20));                  // 1 MB

    prep_xsplit<<<2048, 256, 0, stream>>>(x, xhi, xlo);
    prep_wT<<<dim3(16, 8), 256, 0, stream>>>(W, wth, wtl);
    gemm_qkv_mfma<<<dim3(8, 32), 256, 0, stream>>>(xhi, xlo, wth, wtl, qkv);
    gn_stats<C2, 32><<<dim3(32, BSZ), 256, 0, stream>>>(qkv, meanq, rstdq);
    gn_apply_bf<<<dim3(16, 16, BSZ), 256, 0, stream>>>(qkv, meanq, rstdq, gqs, gqb, qg, qlo, vb);
    prep_relT<<<32, 256, 0, stream>>>(rel, rTb);
    prep_relV<<<512, 256, 0, stream>>>(rel, rVb);
    attn_mfma<<<dim3(LSEQ / BI, NH, BSZ), 512, 0, stream>>>(qg, qlo, vb, rTb, rVb, aout);
    gn_stats<CIN, 16><<<dim3(32, BSZ), 256, 0, stream>>>(aout, meano, rstdo);
    gn_out_apply<<<2048, 256, 0, stream>>>(aout, meano, rstdo, gos, gob, out);
}

// Round 7
// 231.860 us; speedup vs baseline: 7.3306x; 1.2978x over previous
//
#include <hip/hip_runtime.h>
#include <hip/hip_bf16.h>

typedef unsigned short ushort;
typedef __attribute__((ext_vector_type(8))) short bf16x8;
typedef __attribute__((ext_vector_type(4))) float f32x4;
typedef __attribute__((ext_vector_type(4))) unsigned short ushort4v;

#define BSZ  4
#define LSEQ 1024
#define CIN  512
#define C2   1024
#define NH   8
#define GEPS 1e-4f

static __device__ __forceinline__ ushort f2b(float f) {
    __hip_bfloat16 h = __float2bfloat16(f);
    return *reinterpret_cast<ushort*>(&h);
}
static __device__ __forceinline__ float b2f(ushort u) {
    __hip_bfloat16 h = *reinterpret_cast<__hip_bfloat16*>(&u);
    return __bfloat162float(h);
}

// ---------------- P1: split x into hi/lo bf16 ----------------
__global__ __launch_bounds__(256) void prep_xsplit(const float* __restrict__ x,
                                                   ushort* __restrict__ xh,
                                                   ushort* __restrict__ xl) {
    const size_t i4 = (size_t)blockIdx.x * 256 + threadIdx.x;
    const float4 v = *reinterpret_cast<const float4*>(&x[i4 * 4]);
    ushort4v h, lo;
    const float vv[4] = {v.x, v.y, v.z, v.w};
    #pragma unroll
    for (int c = 0; c < 4; ++c) {
        const ushort hh = f2b(vv[c]);
        h[c] = hh;
        lo[c] = f2b(vv[c] - b2f(hh));
    }
    *reinterpret_cast<ushort4v*>(&xh[i4 * 4]) = h;
    *reinterpret_cast<ushort4v*>(&xl[i4 * 4]) = lo;
}

// ---------------- P2: W [512][1024] -> WT hi/lo bf16 [1024][512] ----------------
__global__ __launch_bounds__(256) void prep_wT(const float* __restrict__ W,
                                               ushort* __restrict__ wth,
                                               ushort* __restrict__ wtl) {
    __shared__ float tl[64][65];
    const int k0 = blockIdx.y * 64, n0 = blockIdx.x * 64;
    const int t = threadIdx.x;
    #pragma unroll
    for (int u = 0; u < 16; ++u) {
        const int idx = t + 256 * u;
        const int kk = idx >> 6, nn = idx & 63;
        tl[kk][nn] = W[(size_t)(k0 + kk) * 1024 + n0 + nn];
    }
    __syncthreads();
    #pragma unroll
    for (int u = 0; u < 16; ++u) {
        const int idx = t + 256 * u;
        const int nn = idx >> 6, kk = idx & 63;
        const float v = tl[kk][nn];
        const ushort h = f2b(v);
        wth[(size_t)(n0 + nn) * 512 + k0 + kk] = h;
        wtl[(size_t)(n0 + nn) * 512 + k0 + kk] = f2b(v - b2f(h));
    }
}

// ---------------- P3: fused rel tables: relT[r][d]=bf16(rel[d^32][r]); relV[dv][r]=bf16(rel[64+dv][r]) ----------------
__global__ __launch_bounds__(256) void prep_rel(const float* __restrict__ rel,
                                                ushort* __restrict__ relT,
                                                ushort* __restrict__ relV) {
    const int t = threadIdx.x;
    if (blockIdx.x < 32) {
        __shared__ float tl[64][65];
        const int r0 = blockIdx.x * 64;
        #pragma unroll
        for (int u = 0; u < 16; ++u) {
            const int idx = t + 256 * u;
            const int dd = idx >> 6, rr = idx & 63;
            int r = r0 + rr; if (r > 2046) r = 2046;
            tl[dd][rr] = rel[(size_t)(dd ^ 32) * 2047 + r];
        }
        __syncthreads();
        #pragma unroll
        for (int u = 0; u < 16; ++u) {
            const int idx = t + 256 * u;
            const int rr = idx >> 6, dd = idx & 63;
            relT[(size_t)(r0 + rr) * 64 + dd] = f2b(tl[dd][rr]);
        }
    } else {
        const int idx = (blockIdx.x - 32) * 256 + t;   // 64*2048
        const int dv = idx >> 11, r = idx & 2047;
        const int rc = r > 2046 ? 2046 : r;
        relV[(size_t)dv * 2048 + r] = f2b(rel[(size_t)(64 + dv) * 2047 + rc]);
    }
}

// ---------------- K1: qkv = x @ W via split-bf16 MFMA + fused GN stats ----------------
__global__ __launch_bounds__(256) void gemm_qkv_mfma(const ushort* __restrict__ xh,
                                                     const ushort* __restrict__ xl,
                                                     const ushort* __restrict__ wth,
                                                     const ushort* __restrict__ wtl,
                                                     float* __restrict__ qkv,
                                                     float* __restrict__ sumq) {
    __shared__ ushort Ah[128][40];
    __shared__ ushort Al[128][40];
    __shared__ ushort Bh[128][40];
    __shared__ ushort Bl[128][40];
    const int t = threadIdx.x;
    const int w = t >> 6, l = t & 63;
    const int lr = l & 15, lq = l >> 4;
    const int wm = w >> 1, wn = w & 1;
    const int m0 = blockIdx.y * 128, n0 = blockIdx.x * 128;
    const int b = m0 >> 10;
    f32x4 acc[4][4] = {};
    for (int k0 = 0; k0 < 512; k0 += 32) {
        __syncthreads();
        #pragma unroll
        for (int u = 0; u < 2; ++u) {
            const int idx = t + 256 * u;
            const int r = idx >> 2, c16 = (idx & 3) * 8;
            *(bf16x8*)&Ah[r][c16] = *(const bf16x8*)&xh[(size_t)(m0 + r) * 512 + k0 + c16];
            *(bf16x8*)&Al[r][c16] = *(const bf16x8*)&xl[(size_t)(m0 + r) * 512 + k0 + c16];
            *(bf16x8*)&Bh[r][c16] = *(const bf16x8*)&wth[(size_t)(n0 + r) * 512 + k0 + c16];
            *(bf16x8*)&Bl[r][c16] = *(const bf16x8*)&wtl[(size_t)(n0 + r) * 512 + k0 + c16];
        }
        __syncthreads();
        bf16x8 ah[4], av[4];
        #pragma unroll
        for (int mi = 0; mi < 4; ++mi) {
            ah[mi] = *(const bf16x8*)&Ah[64 * wm + 16 * mi + lr][8 * lq];
            av[mi] = *(const bf16x8*)&Al[64 * wm + 16 * mi + lr][8 * lq];
        }
        #pragma unroll
        for (int ni = 0; ni < 4; ++ni) {
            const bf16x8 bh = *(const bf16x8*)&Bh[64 * wn + 16 * ni + lr][8 * lq];
            const bf16x8 bl = *(const bf16x8*)&Bl[64 * wn + 16 * ni + lr][8 * lq];
            #pragma unroll
            for (int mi = 0; mi < 4; ++mi) {
                f32x4 a = acc[mi][ni];
                a = __builtin_amdgcn_mfma_f32_16x16x32_bf16(ah[mi], bl, a, 0, 0, 0);
                a = __builtin_amdgcn_mfma_f32_16x16x32_bf16(av[mi], bh, a, 0, 0, 0);
                a = __builtin_amdgcn_mfma_f32_16x16x32_bf16(ah[mi], bh, a, 0, 0, 0);
                acc[mi][ni] = a;
            }
        }
    }
    #pragma unroll
    for (int mi = 0; mi < 4; ++mi)
        #pragma unroll
        for (int ni = 0; ni < 4; ++ni)
            #pragma unroll
            for (int e = 0; e < 4; ++e)
                qkv[(size_t)(m0 + 64 * wm + 16 * mi + 4 * lq + e) * 1024 + n0 + 64 * wn + 16 * ni + lr] = acc[mi][ni][e];
    // fused GN stats: per ni-tile, partial sum/sumsq over this wave's 64 rows x 16 cols
    #pragma unroll
    for (int ni = 0; ni < 4; ++ni) {
        float s = 0.f, s2 = 0.f;
        #pragma unroll
        for (int mi = 0; mi < 4; ++mi)
            #pragma unroll
            for (int e = 0; e < 4; ++e) { const float v = acc[mi][ni][e]; s += v; s2 += v * v; }
        #pragma unroll
        for (int o = 32; o; o >>= 1) { s += __shfl_xor(s, o, 64); s2 += __shfl_xor(s2, o, 64); }
        if (l == 0) {
            const int g = (n0 + 64 * wn + 16 * ni) >> 5;
            atomicAdd(&sumq[(b * 32 + g) * 2 + 0], s);
            atomicAdd(&sumq[(b * 32 + g) * 2 + 1], s2);
        }
    }
}

// ---------------- K2: apply qkv GN (inline finalize) -> bf16 qg + lo (q/k) + transposed v ----------------
__global__ __launch_bounds__(256) void gn_apply_bf(const float* __restrict__ qkv,
                                                   const float* __restrict__ sumq,
                                                   const float* __restrict__ scale,
                                                   const float* __restrict__ bias,
                                                   ushort* __restrict__ qg,
                                                   ushort* __restrict__ qlo,
                                                   ushort* __restrict__ vb) {
    __shared__ float tile[64][65];
    const int b  = blockIdx.z;
    const int l0 = blockIdx.y * 64, c0 = blockIdx.x * 64;
    const int t  = threadIdx.x;
    const bool vhalf = (c0 & 64);
    const int h = c0 >> 7;
    #pragma unroll
    for (int u = 0; u < 16; ++u) {
        const int idx = t + 256 * u;
        const int lr = idx >> 6, cr = idx & 63;
        const int c = c0 + cr, g = c >> 5;
        const float s  = sumq[(b * 32 + g) * 2 + 0];
        const float s2 = sumq[(b * 32 + g) * 2 + 1];
        const float mu = s * (1.f / 32768.f);
        const float rr = rsqrtf(fmaxf(s2 * (1.f / 32768.f) - mu * mu, 0.f) + GEPS);
        float v = qkv[(size_t)(b * LSEQ + l0 + lr) * C2 + c];
        v = (v - mu) * rr * scale[c] + bias[c];
        const ushort hi = f2b(v);
        qg[(size_t)(b * LSEQ + l0 + lr) * C2 + c] = hi;
        if (vhalf) tile[lr][cr] = v;
        else qlo[(size_t)(b * LSEQ + l0 + lr) * 512 + h * 64 + cr] = f2b(v - b2f(hi));
    }
    if (vhalf) {
        __syncthreads();
        #pragma unroll
        for (int u = 0; u < 16; ++u) {
            const int idx = t + 256 * u;
            const int cw = idx >> 6, lw = idx & 63;   // cw = dv
            vb[((size_t)((b * NH + h) * 64 + cw)) * LSEQ + l0 + lw] = f2b(tile[lw][cw]);
        }
    }
}

// ---------------- K3: MFMA flash attention — barrier-light, wave-private scratch ----------------
// Each wave w owns rows [i0+16w, i0+16w+16). A-frags in regs; TUb/Ps/Pr are PER-WAVE LDS
// (no barriers needed); rT/rV/vj cooperatively staged (2 barriers/iter); k hi/lo direct global.
// mfma_f32_16x16x32_bf16 conventions: A[m][k],B[n][k] k-contiguous; lane reads row(l&15),
// 8 bf16 at (l>>4)*8; C/D: col=lane&15, row=(lane>>4)*4+e.
__global__ __launch_bounds__(256) void attn_mfma(const ushort* __restrict__ qg,
                                                 const ushort* __restrict__ qlo,
                                                 const ushort* __restrict__ vbuf,
                                                 const ushort* __restrict__ relT,
                                                 const ushort* __restrict__ relV,
                                                 float* __restrict__ aout,
                                                 float* __restrict__ sumo) {
    __shared__ __align__(16) ushort rT[128][72];      // [rl][d]
    __shared__ __align__(16) ushort rV[64][136];      // [dv][rl]
    __shared__ __align__(16) ushort vj[64][72];       // [dv][jj]
    __shared__ __align__(16) ushort TUb[4][16][88];   // per-wave: [row][rl-16w] band
    __shared__ __align__(16) ushort Ps[4][16][72];    // per-wave: [row][jj]
    __shared__ __align__(16) ushort Pr[4][16][104];   // per-wave: [row][rl-32*ck0] band, zero elsewhere

    const int t = threadIdx.x;
    const int w = t >> 6, l = t & 63;
    const int lr = l & 15, lq = l >> 4;
    const int i0 = blockIdx.x * 64;
    const int h = blockIdx.y, b = blockIdx.z;
    const int ck0 = w >> 1;

    // A fragments (constant across the j-loop)
    const size_t arow = (size_t)(b * LSEQ + i0 + 16 * w + lr);
    const bf16x8 a_q  = *(const bf16x8*)&qg[arow * C2 + h * 128 + 8 * lq];
    const bf16x8 a_k  = *(const bf16x8*)&qg[arow * C2 + h * 128 + 32 + 8 * lq];
    const bf16x8 a_ql = *(const bf16x8*)&qlo[arow * 512 + h * 64 + 8 * lq];

    {   // zero private Pr (written band is identical each iter; rest must stay 0)
        uint* pz = (uint*)&Pr[w][0][0];
        #pragma unroll
        for (int u = 0; u < 13; ++u) pz[l + 64 * u] = 0;
    }

    float m_r[4], l_r[4];
    #pragma unroll
    for (int e = 0; e < 4; ++e) { m_r[e] = -3.0e38f; l_r[e] = 0.f; }
    f32x4 Oa[4] = {};

    const size_t vbase = (size_t)((b * NH + h) * 64) * LSEQ;
    const int tbase = 4 * lq + 63 - lr;                       // TU gather base
    const int prbase = 16 * w - 32 * ck0 + 63 + 4 * lq - lr;  // Pr write base

    for (int j0 = 0; j0 < LSEQ; j0 += 64) {
        const int r0 = i0 - j0 + 960;
        __syncthreads();   // prev iter's reads of rT/rV/vj complete
        #pragma unroll
        for (int u = 0; u < 4; ++u) {
            const int idx = t + 256 * u;
            const int rl = idx >> 3, c8 = (idx & 7) * 8;
            *(bf16x8*)&rT[rl][c8] = *(const bf16x8*)&relT[(size_t)(r0 + rl) * 64 + c8];
        }
        #pragma unroll
        for (int u = 0; u < 4; ++u) {
            const int idx = t + 256 * u;
            const int dv = idx >> 4, c8 = (idx & 15) * 8;
            *(bf16x8*)&rV[dv][c8] = *(const bf16x8*)&relV[(size_t)dv * 2048 + r0 + c8];
        }
        #pragma unroll
        for (int u = 0; u < 2; ++u) {
            const int idx = t + 256 * u;
            const int dv = idx >> 3, c8 = (idx & 7) * 8;
            *(bf16x8*)&vj[dv][c8] = *(const bf16x8*)&vbuf[vbase + (size_t)dv * LSEQ + j0 + c8];
        }
        __syncthreads();   // staging visible

        // ---- TU band: 5 tiles ct = w..w+4 (all wave-private from here to loop end) ----
        #pragma unroll
        for (int ct5 = 0; ct5 < 5; ++ct5) {
            const int rr = 16 * (w + ct5) + lr;
            f32x4 acc = {0.f, 0.f, 0.f, 0.f};
            acc = __builtin_amdgcn_mfma_f32_16x16x32_bf16(a_q, *(const bf16x8*)&rT[rr][8 * lq], acc, 0, 0, 0);
            acc = __builtin_amdgcn_mfma_f32_16x16x32_bf16(a_k, *(const bf16x8*)&rT[rr][32 + 8 * lq], acc, 0, 0, 0);
            #pragma unroll
            for (int e = 0; e < 4; ++e) TUb[w][4 * lq + e][16 * ct5 + lr] = f2b(acc[e]);
        }

        // ---- S1 (compensated bf16, k direct from global) + TU skew-gather ----
        f32x4 sv[4];
        #pragma unroll
        for (int n = 0; n < 4; ++n) {
            const size_t krow = (size_t)(b * LSEQ + j0 + 16 * n + lr);
            const bf16x8 b_hi = *(const bf16x8*)&qg[krow * C2 + h * 128 + 32 + 8 * lq];
            const bf16x8 b_lo = *(const bf16x8*)&qlo[krow * 512 + h * 64 + 32 + 8 * lq];
            f32x4 acc = {0.f, 0.f, 0.f, 0.f};
            acc = __builtin_amdgcn_mfma_f32_16x16x32_bf16(a_q,  b_lo, acc, 0, 0, 0);
            acc = __builtin_amdgcn_mfma_f32_16x16x32_bf16(a_ql, b_hi, acc, 0, 0, 0);
            acc = __builtin_amdgcn_mfma_f32_16x16x32_bf16(a_q,  b_hi, acc, 0, 0, 0);
            #pragma unroll
            for (int e = 0; e < 4; ++e) acc[e] += b2f(TUb[w][4 * lq + e][tbase + e - 16 * n]);
            sv[n] = acc;
        }

        // ---- in-wave online softmax (rows owned by (lq,e); 16-lane lr reduce) ----
        float mx[4];
        #pragma unroll
        for (int e = 0; e < 4; ++e)
            mx[e] = fmaxf(fmaxf(sv[0][e], sv[1][e]), fmaxf(sv[2][e], sv[3][e]));
        #pragma unroll
        for (int o = 1; o < 16; o <<= 1)
            #pragma unroll
            for (int e = 0; e < 4; ++e) mx[e] = fmaxf(mx[e], __shfl_xor(mx[e], o, 64));
        float alpha[4], ssum[4];
        #pragma unroll
        for (int e = 0; e < 4; ++e) {
            const float mn = fmaxf(m_r[e], mx[e]);
            alpha[e] = __expf(m_r[e] - mn);
            m_r[e] = mn;
            ssum[e] = 0.f;
        }
        #pragma unroll
        for (int n = 0; n < 4; ++n)
            #pragma unroll
            for (int e = 0; e < 4; ++e) {
                const float p = __expf(sv[n][e] - m_r[e]);
                ssum[e] += p;
                const ushort pb = f2b(p);
                Ps[w][4 * lq + e][16 * n + lr] = pb;
                Pr[w][4 * lq + e][prbase + e - 16 * n] = pb;
            }
        #pragma unroll
        for (int o = 1; o < 16; o <<= 1)
            #pragma unroll
            for (int e = 0; e < 4; ++e) ssum[e] += __shfl_xor(ssum[e], o, 64);
        #pragma unroll
        for (int e = 0; e < 4; ++e) l_r[e] = l_r[e] * alpha[e] + ssum[e];

        // ---- PV: O = diag(alpha)*O + P*v + Pr*rV (banded, 3 chunks) ----
        const bf16x8 pa0 = *(const bf16x8*)&Ps[w][lr][8 * lq];
        const bf16x8 pa1 = *(const bf16x8*)&Ps[w][lr][32 + 8 * lq];
        bf16x8 pra[3];
        #pragma unroll
        for (int kk = 0; kk < 3; ++kk) pra[kk] = *(const bf16x8*)&Pr[w][lr][32 * kk + 8 * lq];
        #pragma unroll
        for (int n = 0; n < 4; ++n) {
            f32x4 acc = Oa[n];
            #pragma unroll
            for (int e = 0; e < 4; ++e) acc[e] *= alpha[e];
            acc = __builtin_amdgcn_mfma_f32_16x16x32_bf16(pa0, *(const bf16x8*)&vj[16 * n + lr][8 * lq], acc, 0, 0, 0);
            acc = __builtin_amdgcn_mfma_f32_16x16x32_bf16(pa1, *(const bf16x8*)&vj[16 * n + lr][32 + 8 * lq], acc, 0, 0, 0);
            #pragma unroll
            for (int kk = 0; kk < 3; ++kk) {
                const bf16x8 brv = *(const bf16x8*)&rV[16 * n + lr][32 * (ck0 + kk) + 8 * lq];
                acc = __builtin_amdgcn_mfma_f32_16x16x32_bf16(pra[kk], brv, acc, 0, 0, 0);
            }
            Oa[n] = acc;
        }
    }

    // ---- epilogue: write O/l + fused out-GN stats ----
    #pragma unroll
    for (int n = 0; n < 4; ++n) {
        float s = 0.f, s2 = 0.f;
        #pragma unroll
        for (int e = 0; e < 4; ++e) {
            const float o = Oa[n][e] / l_r[e];
            aout[((size_t)(b * LSEQ + i0 + 16 * w + 4 * lq + e)) * CIN + h * 64 + 16 * n + lr] = o;
            s += o; s2 += o * o;
        }
        #pragma unroll
        for (int o = 32; o; o >>= 1) { s += __shfl_xor(s, o, 64); s2 += __shfl_xor(s2, o, 64); }
        if (l == 0) {
            atomicAdd(&sumo[(b * 32 + h * 4 + n) * 2 + 0], s);
            atomicAdd(&sumo[(b * 32 + h * 4 + n) * 2 + 1], s2);
        }
    }
}

// ---------------- K4: apply output GN (inline finalize) ----------------
__global__ __launch_bounds__(256) void gn_out_apply(const float* __restrict__ aout,
                                                    const float* __restrict__ sumo,
                                                    const float* __restrict__ scale,
                                                    const float* __restrict__ bias,
                                                    float* __restrict__ out) {
    const int idx4 = blockIdx.x * 256 + threadIdx.x;
    const int c = (idx4 & 127) * 4;
    const size_t row = idx4 >> 7;
    const int b = (int)(row >> 10);
    const int g = c >> 4;
    const float s  = sumo[(b * 32 + g) * 2 + 0];
    const float s2 = sumo[(b * 32 + g) * 2 + 1];
    const float mu = s * (1.f / 16384.f);
    const float rr = rsqrtf(fmaxf(s2 * (1.f / 16384.f) - mu * mu, 0.f) + GEPS);
    const float4 v = *reinterpret_cast<const float4*>(&aout[row * 512 + c]);
    const float4 sc = *reinterpret_cast<const float4*>(&scale[c]);
    const float4 bi = *reinterpret_cast<const float4*>(&bias[c]);
    float4 o;
    o.x = (v.x - mu) * rr * sc.x + bi.x;
    o.y = (v.y - mu) * rr * sc.y + bi.y;
    o.z = (v.z - mu) * rr * sc.z + bi.z;
    o.w = (v.w - mu) * rr * sc.w + bi.w;
    *reinterpret_cast<float4*>(&out[row * 512 + c]) = o;
}

extern "C" void kernel_launch(void* const* d_in, const int* in_sizes, int n_in,
                              void* d_out, int out_size, void* d_ws, size_t ws_size,
                              hipStream_t stream) {
    (void)in_sizes; (void)n_in; (void)out_size; (void)ws_size;
    const float* x   = (const float*)d_in[0];
    const float* W   = (const float*)d_in[1];
    const float* gqs = (const float*)d_in[2];
    const float* gqb = (const float*)d_in[3];
    const float* rel = (const float*)d_in[4];
    const float* gos = (const float*)d_in[5];
    const float* gob = (const float*)d_in[6];
    float* out = (float*)d_out;

    char* ws = (char*)d_ws;
    float*  qkv  = (float*)ws;                                  // 16 MB [b][l][c2] f32
    ushort* qg   = (ushort*)(ws + (16u << 20));                 //  8 MB [b][l][c2] bf16
    ushort* vb   = (ushort*)(ws + (24u << 20));                 //  4 MB [b][h][dv][l]
    ushort* rTb  = (ushort*)(ws + (28u << 20));                 // 256 KB
    ushort* rVb  = (ushort*)(ws + (28u << 20) + (256u << 10));  // 256 KB
    ushort* qlo  = (ushort*)(ws + (28u << 20) + (512u << 10));  //  4 MB [b][l][h*64]
    float*  aout = (float*)ws;                                  // reuse qkv region
    float*  stats = (float*)(ws + (32u << 20) + (512u << 10));  // 2 KB
    float* sumq = stats;          // [b][g][2] raw sums (qkv GN)
    float* sumo = stats + 256;    // [b][g][2] raw sums (out GN)
    // transient (dead after gemm): alias qg/vb regions
    ushort* xhi = (ushort*)(ws + (16u << 20));                  // 4 MB
    ushort* xlo = (ushort*)(ws + (20u << 20));                  // 4 MB
    ushort* wth = (ushort*)(ws + (24u << 20));                  // 1 MB
    ushort* wtl = (ushort*)(ws + (25u << 20));                  // 1 MB

    hipMemsetAsync(stats, 0, 2048, stream);
    prep_xsplit<<<2048, 256, 0, stream>>>(x, xhi, xlo);
    prep_wT<<<dim3(16, 8), 256, 0, stream>>>(W, wth, wtl);
    prep_rel<<<544, 256, 0, stream>>>(rel, rTb, rVb);
    gemm_qkv_mfma<<<dim3(8, 32), 256, 0, stream>>>(xhi, xlo, wth, wtl, qkv, sumq);
    gn_apply_bf<<<dim3(16, 16, BSZ), 256, 0, stream>>>(qkv, sumq, gqs, gqb, qg, qlo, vb);
    attn_mfma<<<dim3(16, NH, BSZ), 256, 0, stream>>>(qg, qlo, vb, rTb, rVb, aout, sumo);
    gn_out_apply<<<2048, 256, 0, stream>>>(aout, sumo, gos, gob, out);
}